// Round 4
// baseline (410.089 us; speedup 1.0000x reference)
//
#include <hip/hip_runtime.h>
#include <hip/hip_fp16.h>
#include <cstdint>

#define HIDDEN 1024
#define ATTN   512
#define NB     8
#define SEQ    2048
#define MROWS  (NB*SEQ)   // 16384

typedef _Float16 f16x8 __attribute__((ext_vector_type(8)));
typedef float    f32x4 __attribute__((ext_vector_type(4)));

__device__ __forceinline__ float tanh_fast(float x){
  float e = __expf(2.0f*x);
  return 1.0f - 2.0f/(e + 1.0f);
}

__device__ __forceinline__ void gload16(const void* g, void* l){
  __builtin_amdgcn_global_load_lds((const __attribute__((address_space(1))) void*)g,
                                   (__attribute__((address_space(3))) void*)l, 16, 0, 0);
}

// ---------------- K0a: cast inputs f32 -> fp16 ----------------
__global__ __launch_bounds__(256) void k_cast_x(const float* __restrict__ x, __half* __restrict__ xh){
  size_t i = (size_t)blockIdx.x*256 + threadIdx.x;
  const float4* src = reinterpret_cast<const float4*>(x) + i*2;
  float4 a = src[0], b = src[1];
  f16x8 h;
  h[0]=(_Float16)a.x; h[1]=(_Float16)a.y; h[2]=(_Float16)a.z; h[3]=(_Float16)a.w;
  h[4]=(_Float16)b.x; h[5]=(_Float16)b.y; h[6]=(_Float16)b.z; h[7]=(_Float16)b.w;
  reinterpret_cast<f16x8*>(xh)[i] = h;
}

// ---------------- K0b: W[1024][512] f32 -> WhT[512][1024] fp16 (x3) ----------------
__global__ __launch_bounds__(256) void k_transpose_w(const float* __restrict__ Wq, const float* __restrict__ Wk,
                                                     const float* __restrict__ Wv, __half* __restrict__ whT){
  __shared__ float lds[32][33];
  int which = blockIdx.y;
  const float* W = which==0 ? Wq : (which==1 ? Wk : Wv);
  int tr = blockIdx.x >> 4;
  int tc = blockIdx.x & 15;
  int t = threadIdx.x;
  {
    int r = t >> 3, c4 = (t & 7)*4;
    float4 v = *reinterpret_cast<const float4*>(W + (size_t)(tr*32 + r)*ATTN + tc*32 + c4);
    lds[r][c4+0]=v.x; lds[r][c4+1]=v.y; lds[r][c4+2]=v.z; lds[r][c4+3]=v.w;
  }
  __syncthreads();
  {
    int n = t >> 3, k4 = (t & 7)*4;
    ushort4 u;
    u.x = __half_as_ushort(__float2half(lds[k4+0][n]));
    u.y = __half_as_ushort(__float2half(lds[k4+1][n]));
    u.z = __half_as_ushort(__float2half(lds[k4+2][n]));
    u.w = __half_as_ushort(__float2half(lds[k4+3][n]));
    *reinterpret_cast<ushort4*>(whT + (size_t)which*ATTN*HIDDEN + (size_t)(tc*32 + n)*HIDDEN + tr*32 + k4) = u;
  }
}

// ---------------- K1: fused QKV projection, q/k/v = tanh(x@W + b), fp16 out ----------------
// 128x128 tile, BK=64 (2 barriers / 64 K => half the drain stalls of BK=32), 256 thr (4 waves, 2x2).
// global_load_lds w16 with pre-swizzled source; st_16x32-style swizzle phys_slot = s ^ (row&7).
__global__ __launch_bounds__(256,3) void k_proj(const __half* __restrict__ xh, const __half* __restrict__ whT,
                                                const float* __restrict__ bq, const float* __restrict__ bk,
                                                const float* __restrict__ bv,
                                                __half* __restrict__ qh, __half* __restrict__ kh, __half* __restrict__ vh){
  __shared__ __align__(16) _Float16 lA[128*64];   // 16 KB
  __shared__ __align__(16) _Float16 lB[128*64];   // 16 KB
  int nt = blockIdx.x;             // 0..11 : which = nt>>2, 128-col slab = nt&3
  int m0 = blockIdx.y * 128;
  int which = nt >> 2;
  int ncol0 = (nt & 3) * 128;
  int t = threadIdx.x;
  int w = t >> 6, lane = t & 63;
  int lrow = lane & 15, lk = lane >> 4;
  int wm = w >> 1, wn = w & 1;

  // staging: wave w stages tile rows [w*32, w*32+32) of A and B, 4 chunks of 8 rows.
  // chunk: 64 lanes x 16B = 8 rows x 8 slots; rr = lane>>3 (row in chunk), phys slot = lane&7,
  // logical k-slot at source: s = (lane&7) ^ rr   (since tile_row & 7 == rr).
  int rr = lane >> 3;
  int ss = (lane & 7) ^ rr;
  const __half* Abase = xh + (size_t)(m0 + w*32 + rr)*HIDDEN + ss*8;
  const __half* Bbase = whT + (size_t)which*ATTN*HIDDEN + (size_t)(ncol0 + w*32 + rr)*HIDDEN + ss*8;
  _Float16* lAw = &lA[(w*32)*64];
  _Float16* lBw = &lB[(w*32)*64];

  f32x4 acc[4][4];
  #pragma unroll
  for (int i=0;i<4;i++)
    #pragma unroll
    for (int j=0;j<4;j++) acc[i][j] = f32x4{0.f,0.f,0.f,0.f};

  for (int k0 = 0; k0 < HIDDEN; k0 += 64){
    __syncthreads();                       // previous compute done reading LDS
    #pragma unroll
    for (int c=0; c<4; c++){
      gload16(Abase + (size_t)c*8*HIDDEN + k0, &lAw[c*8*64]);
      gload16(Bbase + (size_t)c*8*HIDDEN + k0, &lBw[c*8*64]);
    }
    __syncthreads();                       // barrier drains vmcnt -> LDS ready
    #pragma unroll
    for (int u=0; u<2; u++){
      f16x8 af[4], bf[4];
      #pragma unroll
      for (int fm=0; fm<4; fm++){
        int row = wm*64 + fm*16 + lrow;
        af[fm] = *(const f16x8*)&lA[row*64 + (((u*4 + lk) ^ (row & 7))*8)];
      }
      #pragma unroll
      for (int fn=0; fn<4; fn++){
        int row = wn*64 + fn*16 + lrow;
        bf[fn] = *(const f16x8*)&lB[row*64 + (((u*4 + lk) ^ (row & 7))*8)];
      }
      #pragma unroll
      for (int fm=0; fm<4; fm++)
        #pragma unroll
        for (int fn=0; fn<4; fn++)
          acc[fm][fn] = __builtin_amdgcn_mfma_f32_16x16x32_f16(af[fm], bf[fn], acc[fm][fn], 0,0,0);
    }
  }

  const float* bias = which==0 ? bq : (which==1 ? bk : bv);
  __half* dst = which==0 ? qh : (which==1 ? kh : vh);
  #pragma unroll
  for (int fn=0; fn<4; fn++){
    int col = ncol0 + wn*64 + fn*16 + lrow;
    float bb = bias[col];
    #pragma unroll
    for (int fm=0; fm<4; fm++)
      #pragma unroll
      for (int mi=0; mi<4; mi++){
        int row = m0 + wm*64 + fm*16 + lk*4 + mi;
        dst[(size_t)row*ATTN + col] = __float2half(tanh_fast(acc[fm][fn][mi] + bb));
      }
  }
}

// ---------------- K1b: vh[16384][512] -> vT[8][512][2048] (per-batch transpose) ----------------
__global__ __launch_bounds__(256) void k_transpose_v(const __half* __restrict__ vh, __half* __restrict__ vT){
  __shared__ _Float16 lds[64][80];
  int r0 = blockIdx.x * 64;
  int c0 = blockIdx.y * 64;
  int b = r0 / SEQ, j0 = r0 % SEQ;
  int t = threadIdx.x;
  #pragma unroll
  for (int it=0; it<2; it++){
    int g = it*256 + t;
    int r = g >> 3, s = g & 7;
    f16x8 v = *(const f16x8*)(vh + (size_t)(r0 + r)*ATTN + c0 + s*8);
    #pragma unroll
    for (int i=0;i<8;i++) lds[s*8+i][r] = v[i];
  }
  __syncthreads();
  #pragma unroll
  for (int it=0; it<2; it++){
    int g = it*256 + t;
    int ar = g >> 3, s = g & 7;
    f16x8 v = *(const f16x8*)&lds[ar][s*8];
    *(f16x8*)(vT + ((size_t)b*ATTN + c0 + ar)*SEQ + j0 + s*8) = v;
  }
}

// ---------------- K2: scores + softmax -> probs (f32), fused per 32-row q-block ----------------
// XCD-pin: batch = bid&7 so each XCD's L2 holds exactly one batch's kh slice (2 MB < 4 MB L2).
__global__ __launch_bounds__(512,2) void k_scores(const __half* __restrict__ qh, const __half* __restrict__ kh,
                                                  float* __restrict__ probs){
  __shared__ float red[8][32];
  int bid = blockIdx.x;
  int b  = bid & 7;            // batch pinned to XCD (round-robin dispatch assumption; perf-only)
  int i0 = (bid >> 3) * 32;
  int t = threadIdx.x;
  int w = t >> 6, lane = t & 63;
  int lrow = lane & 15, lk = lane >> 4;
  size_t qrow0 = (size_t)b*SEQ + i0;
  size_t krow0 = (size_t)b*SEQ;

  f32x4 acc[2][16];
  #pragma unroll
  for (int i=0;i<2;i++)
    #pragma unroll
    for (int j=0;j<16;j++) acc[i][j] = f32x4{0.f,0.f,0.f,0.f};

  for (int k0 = 0; k0 < ATTN; k0 += 32){
    f16x8 aq0 = *(const f16x8*)(qh + (qrow0 + lrow)*ATTN      + k0 + lk*8);
    f16x8 aq1 = *(const f16x8*)(qh + (qrow0 + 16 + lrow)*ATTN + k0 + lk*8);
    #pragma unroll
    for (int fn=0; fn<16; fn++){
      f16x8 bk8 = *(const f16x8*)(kh + (krow0 + w*256 + fn*16 + lrow)*ATTN + k0 + lk*8);
      acc[0][fn] = __builtin_amdgcn_mfma_f32_16x16x32_f16(aq0, bk8, acc[0][fn], 0,0,0);
      acc[1][fn] = __builtin_amdgcn_mfma_f32_16x16x32_f16(aq1, bk8, acc[1][fn], 0,0,0);
    }
  }

  const float scale = 0.044194173824159216f;   // 1/sqrt(512)
  #pragma unroll
  for (int fm=0;fm<2;fm++)
    #pragma unroll
    for (int fn=0;fn<16;fn++) acc[fm][fn] *= scale;

  float mx[2][4], gm[2][4], sm[2][4];
  #pragma unroll
  for (int fm=0;fm<2;fm++)
    #pragma unroll
    for (int mi=0;mi<4;mi++){
      float m = -1e30f;
      #pragma unroll
      for (int fn=0;fn<16;fn++) m = fmaxf(m, acc[fm][fn][mi]);
      #pragma unroll
      for (int off=8; off>=1; off>>=1) m = fmaxf(m, __shfl_xor(m, off, 16));
      mx[fm][mi] = m;
    }
  if (lrow == 0){
    #pragma unroll
    for (int fm=0;fm<2;fm++)
      #pragma unroll
      for (int mi=0;mi<4;mi++) red[w][fm*16 + lk*4 + mi] = mx[fm][mi];
  }
  __syncthreads();
  #pragma unroll
  for (int fm=0;fm<2;fm++)
    #pragma unroll
    for (int mi=0;mi<4;mi++){
      int r = fm*16 + lk*4 + mi;
      float m = red[0][r];
      #pragma unroll
      for (int ww=1; ww<8; ww++) m = fmaxf(m, red[ww][r]);
      gm[fm][mi] = m;
    }
  __syncthreads();
  #pragma unroll
  for (int fm=0;fm<2;fm++)
    #pragma unroll
    for (int mi=0;mi<4;mi++){
      float s = 0.f;
      #pragma unroll
      for (int fn=0;fn<16;fn++){
        float e = __expf(acc[fm][fn][mi] - gm[fm][mi]);
        acc[fm][fn][mi] = e;
        s += e;
      }
      #pragma unroll
      for (int off=8; off>=1; off>>=1) s += __shfl_xor(s, off, 16);
      sm[fm][mi] = s;
    }
  if (lrow == 0){
    #pragma unroll
    for (int fm=0;fm<2;fm++)
      #pragma unroll
      for (int mi=0;mi<4;mi++) red[w][fm*16 + lk*4 + mi] = sm[fm][mi];
  }
  __syncthreads();
  float* dst = probs + ((size_t)b*SEQ)*SEQ;
  #pragma unroll
  for (int fm=0;fm<2;fm++)
    #pragma unroll
    for (int mi=0;mi<4;mi++){
      int r = fm*16 + lk*4 + mi;
      float tot = 0.f;
      #pragma unroll
      for (int ww=0; ww<8; ww++) tot += red[ww][r];
      float inv = 1.0f / tot;
      size_t rowoff = (size_t)(i0 + r)*SEQ + w*256 + lrow;
      #pragma unroll
      for (int fn=0;fn<16;fn++) dst[rowoff + fn*16] = acc[fm][fn][mi]*inv;
    }
}

// ---------------- K3: context = probs @ v, out0 = tanh(context) ----------------
__global__ __launch_bounds__(512,2) void k_pv(const float* __restrict__ probs, const __half* __restrict__ vT,
                                              float* __restrict__ out0){
  __shared__ __align__(16) _Float16 lA[64*64];   // 8 KB, rows of 128B, slot-swizzled
  int bid = blockIdx.x;
  int b  = bid & 7;            // XCD remap: vT[b] L2-resident
  int i0 = (bid >> 3) * 64;
  int t = threadIdx.x;
  int w = t >> 6, lane = t & 63;
  int lrow = lane & 15, lk = lane >> 4;
  int wm = w >> 2, wn = w & 3;          // wave = 32 rows x 128 cols
  int sr = t >> 3, ssc = t & 7;         // staging: 8 thr/row, 8 f32 each

  const float*  psrc  = probs + ((size_t)b*SEQ + i0 + sr)*SEQ + ssc*8;
  const __half* vbase = vT + (size_t)b*ATTN*SEQ;
  int dst_sl = (ssc ^ (sr & 7)) * 8;    // swizzled LDS slot (halfs) for staging write

  f32x4 acc[2][8];
  #pragma unroll
  for (int i=0;i<2;i++)
    #pragma unroll
    for (int j=0;j<8;j++) acc[i][j] = f32x4{0.f,0.f,0.f,0.f};

  float4 p0 = *(const float4*)(psrc);
  float4 p1 = *(const float4*)(psrc + 4);

  for (int k0 = 0; k0 < SEQ; k0 += 64){
    f16x8 hv;
    hv[0]=(_Float16)p0.x; hv[1]=(_Float16)p0.y; hv[2]=(_Float16)p0.z; hv[3]=(_Float16)p0.w;
    hv[4]=(_Float16)p1.x; hv[5]=(_Float16)p1.y; hv[6]=(_Float16)p1.z; hv[7]=(_Float16)p1.w;
    __syncthreads();
    *(f16x8*)&lA[sr*64 + dst_sl] = hv;
    __syncthreads();
    if (k0 + 64 < SEQ){
      p0 = *(const float4*)(psrc + k0 + 64);
      p1 = *(const float4*)(psrc + k0 + 68);
    }
    #pragma unroll
    for (int u=0; u<2; u++){
      f16x8 af[2];
      #pragma unroll
      for (int fm=0; fm<2; fm++){
        int row = wm*32 + fm*16 + lrow;
        af[fm] = *(const f16x8*)&lA[row*64 + (((u*4 + lk) ^ (row & 7))*8)];
      }
      #pragma unroll
      for (int fn=0; fn<8; fn++){
        f16x8 bv8 = *(const f16x8*)(vbase + (size_t)(wn*128 + fn*16 + lrow)*SEQ + k0 + u*32 + lk*8);
        #pragma unroll
        for (int fm=0; fm<2; fm++)
          acc[fm][fn] = __builtin_amdgcn_mfma_f32_16x16x32_f16(af[fm], bv8, acc[fm][fn], 0,0,0);
      }
    }
  }

  float* dst = out0 + ((size_t)b*SEQ + i0)*ATTN;
  #pragma unroll
  for (int fm=0; fm<2; fm++)
    #pragma unroll
    for (int fn=0; fn<8; fn++)
      #pragma unroll
      for (int mi=0; mi<4; mi++)
        dst[(size_t)(wm*32 + fm*16 + lk*4 + mi)*ATTN + wn*128 + fn*16 + lrow] = tanh_fast(acc[fm][fn][mi]);
}

extern "C" void kernel_launch(void* const* d_in, const int* in_sizes, int n_in,
                              void* d_out, int out_size, void* d_ws, size_t ws_size,
                              hipStream_t stream){
  const float* x  = (const float*)d_in[0];
  const float* Wq = (const float*)d_in[1];
  const float* bq = (const float*)d_in[2];
  const float* Wk = (const float*)d_in[3];
  const float* bk = (const float*)d_in[4];
  const float* Wv = (const float*)d_in[5];
  const float* bv = (const float*)d_in[6];

  float* out0 = (float*)d_out;                        // [8,2048,512]  tanh(context)   33.55 MB
  float* out1 = out0 + (size_t)NB*SEQ*ATTN;           // [8,2048,2048] probs          134.2 MB

  // Overlay (d_ws use: 16.78 MB):
  //  out0 region (written only by final k_pv):  qh | kh
  //  out1 region (written only by k_scores):    xh | whT | vh
  //  d_ws:                                      vT (must survive probs write)
  __half* qh  = (__half*)out0;
  __half* kh  = (__half*)out0 + (size_t)MROWS*ATTN;
  __half* xh  = (__half*)out1;
  __half* whT = (__half*)((char*)out1 + 33554432);
  __half* vh  = (__half*)((char*)out1 + 36700160);
  __half* vT  = (__half*)d_ws;

  k_cast_x     <<<8192,        256, 0, stream>>>(x, xh);
  k_transpose_w<<<dim3(512,3), 256, 0, stream>>>(Wq, Wk, Wv, whT);
  k_proj       <<<dim3(12,128),256, 0, stream>>>(xh, whT, bq, bk, bv, qh, kh, vh);
  k_transpose_v<<<dim3(256,8), 256, 0, stream>>>(vh, vT);
  k_scores     <<<512,         512, 0, stream>>>(qh, kh, out1);
  k_pv         <<<256,         512, 0, stream>>>(out1, vT, out0);
}

// Round 5
// 404.204 us; speedup vs baseline: 1.0146x; 1.0146x over previous
//
#include <hip/hip_runtime.h>
#include <hip/hip_fp16.h>
#include <cstdint>

#define HIDDEN 1024
#define ATTN   512
#define NB     8
#define SEQ    2048
#define MROWS  (NB*SEQ)   // 16384

typedef _Float16 f16x8 __attribute__((ext_vector_type(8)));
typedef float    f32x4 __attribute__((ext_vector_type(4)));

__device__ __forceinline__ float tanh_fast(float x){
  float e = __expf(2.0f*x);
  return 1.0f - 2.0f/(e + 1.0f);
}

__device__ __forceinline__ void gload16(const void* g, void* l){
  __builtin_amdgcn_global_load_lds((const __attribute__((address_space(1))) void*)g,
                                   (__attribute__((address_space(3))) void*)l, 16, 0, 0);
}

// ---------------- K0a: cast inputs f32 -> fp16 ----------------
__global__ __launch_bounds__(256) void k_cast_x(const float* __restrict__ x, __half* __restrict__ xh){
  size_t i = (size_t)blockIdx.x*256 + threadIdx.x;
  const float4* src = reinterpret_cast<const float4*>(x) + i*2;
  float4 a = src[0], b = src[1];
  f16x8 h;
  h[0]=(_Float16)a.x; h[1]=(_Float16)a.y; h[2]=(_Float16)a.z; h[3]=(_Float16)a.w;
  h[4]=(_Float16)b.x; h[5]=(_Float16)b.y; h[6]=(_Float16)b.z; h[7]=(_Float16)b.w;
  reinterpret_cast<f16x8*>(xh)[i] = h;
}

// ---------------- K0b: W[1024][512] f32 -> WhT[512][1024] fp16 (x3) ----------------
__global__ __launch_bounds__(256) void k_transpose_w(const float* __restrict__ Wq, const float* __restrict__ Wk,
                                                     const float* __restrict__ Wv, __half* __restrict__ whT){
  __shared__ float lds[32][33];
  int which = blockIdx.y;
  const float* W = which==0 ? Wq : (which==1 ? Wk : Wv);
  int tr = blockIdx.x >> 4;
  int tc = blockIdx.x & 15;
  int t = threadIdx.x;
  {
    int r = t >> 3, c4 = (t & 7)*4;
    float4 v = *reinterpret_cast<const float4*>(W + (size_t)(tr*32 + r)*ATTN + tc*32 + c4);
    lds[r][c4+0]=v.x; lds[r][c4+1]=v.y; lds[r][c4+2]=v.z; lds[r][c4+3]=v.w;
  }
  __syncthreads();
  {
    int n = t >> 3, k4 = (t & 7)*4;
    ushort4 u;
    u.x = __half_as_ushort(__float2half(lds[k4+0][n]));
    u.y = __half_as_ushort(__float2half(lds[k4+1][n]));
    u.z = __half_as_ushort(__float2half(lds[k4+2][n]));
    u.w = __half_as_ushort(__float2half(lds[k4+3][n]));
    *reinterpret_cast<ushort4*>(whT + (size_t)which*ATTN*HIDDEN + (size_t)(tc*32 + n)*HIDDEN + tr*32 + k4) = u;
  }
}

// ---------------- K1: fused QKV projection, q/k/v = tanh(x@W + b), fp16 out ----------------
__global__ __launch_bounds__(256,3) void k_proj(const __half* __restrict__ xh, const __half* __restrict__ whT,
                                                const float* __restrict__ bq, const float* __restrict__ bk,
                                                const float* __restrict__ bv,
                                                __half* __restrict__ qh, __half* __restrict__ kh, __half* __restrict__ vh){
  __shared__ __align__(16) _Float16 lA[128*64];   // 16 KB
  __shared__ __align__(16) _Float16 lB[128*64];   // 16 KB
  int nt = blockIdx.x;             // 0..11 : which = nt>>2, 128-col slab = nt&3
  int m0 = blockIdx.y * 128;
  int which = nt >> 2;
  int ncol0 = (nt & 3) * 128;
  int t = threadIdx.x;
  int w = t >> 6, lane = t & 63;
  int lrow = lane & 15, lk = lane >> 4;
  int wm = w >> 1, wn = w & 1;

  int rr = lane >> 3;
  int ss = (lane & 7) ^ rr;
  const __half* Abase = xh + (size_t)(m0 + w*32 + rr)*HIDDEN + ss*8;
  const __half* Bbase = whT + (size_t)which*ATTN*HIDDEN + (size_t)(ncol0 + w*32 + rr)*HIDDEN + ss*8;
  _Float16* lAw = &lA[(w*32)*64];
  _Float16* lBw = &lB[(w*32)*64];

  f32x4 acc[4][4];
  #pragma unroll
  for (int i=0;i<4;i++)
    #pragma unroll
    for (int j=0;j<4;j++) acc[i][j] = f32x4{0.f,0.f,0.f,0.f};

  for (int k0 = 0; k0 < HIDDEN; k0 += 64){
    __syncthreads();
    #pragma unroll
    for (int c=0; c<4; c++){
      gload16(Abase + (size_t)c*8*HIDDEN + k0, &lAw[c*8*64]);
      gload16(Bbase + (size_t)c*8*HIDDEN + k0, &lBw[c*8*64]);
    }
    __syncthreads();
    #pragma unroll
    for (int u=0; u<2; u++){
      f16x8 af[4], bf[4];
      #pragma unroll
      for (int fm=0; fm<4; fm++){
        int row = wm*64 + fm*16 + lrow;
        af[fm] = *(const f16x8*)&lA[row*64 + (((u*4 + lk) ^ (row & 7))*8)];
      }
      #pragma unroll
      for (int fn=0; fn<4; fn++){
        int row = wn*64 + fn*16 + lrow;
        bf[fn] = *(const f16x8*)&lB[row*64 + (((u*4 + lk) ^ (row & 7))*8)];
      }
      #pragma unroll
      for (int fm=0; fm<4; fm++)
        #pragma unroll
        for (int fn=0; fn<4; fn++)
          acc[fm][fn] = __builtin_amdgcn_mfma_f32_16x16x32_f16(af[fm], bf[fn], acc[fm][fn], 0,0,0);
    }
  }

  const float* bias = which==0 ? bq : (which==1 ? bk : bv);
  __half* dst = which==0 ? qh : (which==1 ? kh : vh);
  #pragma unroll
  for (int fn=0; fn<4; fn++){
    int col = ncol0 + wn*64 + fn*16 + lrow;
    float bb = bias[col];
    #pragma unroll
    for (int fm=0; fm<4; fm++)
      #pragma unroll
      for (int mi=0; mi<4; mi++){
        int row = m0 + wm*64 + fm*16 + lk*4 + mi;
        dst[(size_t)row*ATTN + col] = __float2half(tanh_fast(acc[fm][fn][mi] + bb));
      }
  }
}

// ---------------- K1b: vh[16384][512] -> vT[8][512][2048] (per-batch transpose) ----------------
__global__ __launch_bounds__(256) void k_transpose_v(const __half* __restrict__ vh, __half* __restrict__ vT){
  __shared__ _Float16 lds[64][80];
  int r0 = blockIdx.x * 64;
  int c0 = blockIdx.y * 64;
  int b = r0 / SEQ, j0 = r0 % SEQ;
  int t = threadIdx.x;
  #pragma unroll
  for (int it=0; it<2; it++){
    int g = it*256 + t;
    int r = g >> 3, s = g & 7;
    f16x8 v = *(const f16x8*)(vh + (size_t)(r0 + r)*ATTN + c0 + s*8);
    #pragma unroll
    for (int i=0;i<8;i++) lds[s*8+i][r] = v[i];
  }
  __syncthreads();
  #pragma unroll
  for (int it=0; it<2; it++){
    int g = it*256 + t;
    int ar = g >> 3, s = g & 7;
    f16x8 v = *(const f16x8*)&lds[ar][s*8];
    *(f16x8*)(vT + ((size_t)b*ATTN + c0 + ar)*SEQ + j0 + s*8) = v;
  }
}

// ---------------- K2: scores + softmax -> probs (f32), swapped-operand, 16 waves ----------------
// Sᵀ = mfma(K_frag, Q_frag): lane holds 4 CONSECUTIVE keys per q-row -> float4 probs stores.
// 1024 thr = 16 waves, 128 keys/wave; acc 64 f32/lane -> <=128 VGPR -> 4 waves/SIMD.
__global__ __launch_bounds__(1024,4) void k_scores(const __half* __restrict__ qh, const __half* __restrict__ kh,
                                                   float* __restrict__ probs){
  __shared__ float red[16][32];
  int bid = blockIdx.x;
  int b  = bid & 7;            // XCD pin: batch's kh slice (2 MB) resident in one XCD L2
  int i0 = (bid >> 3) * 32;
  int t = threadIdx.x;
  int w = t >> 6, lane = t & 63;
  int lrow = lane & 15, lk = lane >> 4;
  size_t qrow0 = (size_t)b*SEQ + i0;
  size_t krow0 = (size_t)b*SEQ + w*128;

  f32x4 acc[2][8];             // [nf: q-rows 0-15 / 16-31][fn: key-frag of 16]
  #pragma unroll
  for (int i=0;i<2;i++)
    #pragma unroll
    for (int j=0;j<8;j++) acc[i][j] = f32x4{0.f,0.f,0.f,0.f};

  for (int k0 = 0; k0 < ATTN; k0 += 32){
    f16x8 aq0 = *(const f16x8*)(qh + (qrow0 + lrow)*ATTN      + k0 + lk*8);
    f16x8 aq1 = *(const f16x8*)(qh + (qrow0 + 16 + lrow)*ATTN + k0 + lk*8);
    #pragma unroll
    for (int fn=0; fn<8; fn++){
      f16x8 kf = *(const f16x8*)(kh + (krow0 + fn*16 + lrow)*ATTN + k0 + lk*8);
      acc[0][fn] = __builtin_amdgcn_mfma_f32_16x16x32_f16(kf, aq0, acc[0][fn], 0,0,0);
      acc[1][fn] = __builtin_amdgcn_mfma_f32_16x16x32_f16(kf, aq1, acc[1][fn], 0,0,0);
    }
  }

  const float scale = 0.044194173824159216f;   // 1/sqrt(512)
  #pragma unroll
  for (int nf=0;nf<2;nf++)
    #pragma unroll
    for (int fn=0;fn<8;fn++) acc[nf][fn] *= scale;

  // per-q-row max: lane-local (32 vals) then butterfly over lk lanes (xor 16, 32)
  float mx[2];
  #pragma unroll
  for (int nf=0;nf<2;nf++){
    float m = -1e30f;
    #pragma unroll
    for (int fn=0;fn<8;fn++)
      #pragma unroll
      for (int mi=0;mi<4;mi++) m = fmaxf(m, acc[nf][fn][mi]);
    m = fmaxf(m, __shfl_xor(m, 16));
    m = fmaxf(m, __shfl_xor(m, 32));
    mx[nf] = m;
  }
  if (lane < 16){ red[w][lane] = mx[0]; red[w][16 + lane] = mx[1]; }
  __syncthreads();
  float gm[2];
  #pragma unroll
  for (int nf=0;nf<2;nf++){
    float m = red[0][nf*16 + lrow];
    #pragma unroll
    for (int ww=1; ww<16; ww++) m = fmaxf(m, red[ww][nf*16 + lrow]);
    gm[nf] = m;
  }
  __syncthreads();
  // exp + sum
  float sm[2];
  #pragma unroll
  for (int nf=0;nf<2;nf++){
    float s = 0.f;
    #pragma unroll
    for (int fn=0;fn<8;fn++)
      #pragma unroll
      for (int mi=0;mi<4;mi++){
        float e = __expf(acc[nf][fn][mi] - gm[nf]);
        acc[nf][fn][mi] = e;
        s += e;
      }
    s += __shfl_xor(s, 16);
    s += __shfl_xor(s, 32);
    sm[nf] = s;
  }
  if (lane < 16){ red[w][lane] = sm[0]; red[w][16 + lane] = sm[1]; }
  __syncthreads();
  float inv[2];
  #pragma unroll
  for (int nf=0;nf<2;nf++){
    float tot = 0.f;
    #pragma unroll
    for (int ww=0; ww<16; ww++) tot += red[ww][nf*16 + lrow];
    inv[nf] = 1.0f / tot;
  }
  // float4 stores: lane covers keys w*128 + fn*16 + lk*4 .. +3 of q-row i0 + nf*16 + lrow
  float* dst = probs + (size_t)b*SEQ*SEQ;
  #pragma unroll
  for (int nf=0;nf<2;nf++){
    size_t rowoff = (size_t)(i0 + nf*16 + lrow)*SEQ + w*128 + lk*4;
    f32x4 iv = {inv[nf], inv[nf], inv[nf], inv[nf]};
    #pragma unroll
    for (int fn=0;fn<8;fn++){
      f32x4 v = acc[nf][fn] * iv;
      *(float4*)(dst + rowoff + fn*16) = *(float4*)&v;
    }
  }
}

// ---------------- K3: context = probs @ v, out0 = tanh(context) ----------------
__global__ __launch_bounds__(512,2) void k_pv(const float* __restrict__ probs, const __half* __restrict__ vT,
                                              float* __restrict__ out0){
  __shared__ __align__(16) _Float16 lA[64*64];   // 8 KB
  int bid = blockIdx.x;
  int b  = bid & 7;
  int i0 = (bid >> 3) * 64;
  int t = threadIdx.x;
  int w = t >> 6, lane = t & 63;
  int lrow = lane & 15, lk = lane >> 4;
  int wm = w >> 2, wn = w & 3;
  int sr = t >> 3, ssc = t & 7;

  const float*  psrc  = probs + ((size_t)b*SEQ + i0 + sr)*SEQ + ssc*8;
  const __half* vbase = vT + (size_t)b*ATTN*SEQ;
  int dst_sl = (ssc ^ (sr & 7)) * 8;

  f32x4 acc[2][8];
  #pragma unroll
  for (int i=0;i<2;i++)
    #pragma unroll
    for (int j=0;j<8;j++) acc[i][j] = f32x4{0.f,0.f,0.f,0.f};

  float4 p0 = *(const float4*)(psrc);
  float4 p1 = *(const float4*)(psrc + 4);

  for (int k0 = 0; k0 < SEQ; k0 += 64){
    f16x8 hv;
    hv[0]=(_Float16)p0.x; hv[1]=(_Float16)p0.y; hv[2]=(_Float16)p0.z; hv[3]=(_Float16)p0.w;
    hv[4]=(_Float16)p1.x; hv[5]=(_Float16)p1.y; hv[6]=(_Float16)p1.z; hv[7]=(_Float16)p1.w;
    __syncthreads();
    *(f16x8*)&lA[sr*64 + dst_sl] = hv;
    __syncthreads();
    if (k0 + 64 < SEQ){
      p0 = *(const float4*)(psrc + k0 + 64);
      p1 = *(const float4*)(psrc + k0 + 68);
    }
    #pragma unroll
    for (int u=0; u<2; u++){
      f16x8 af[2];
      #pragma unroll
      for (int fm=0; fm<2; fm++){
        int row = wm*32 + fm*16 + lrow;
        af[fm] = *(const f16x8*)&lA[row*64 + (((u*4 + lk) ^ (row & 7))*8)];
      }
      #pragma unroll
      for (int fn=0; fn<8; fn++){
        f16x8 bv8 = *(const f16x8*)(vbase + (size_t)(wn*128 + fn*16 + lrow)*SEQ + k0 + u*32 + lk*8);
        #pragma unroll
        for (int fm=0; fm<2; fm++)
          acc[fm][fn] = __builtin_amdgcn_mfma_f32_16x16x32_f16(af[fm], bv8, acc[fm][fn], 0,0,0);
      }
    }
  }

  float* dst = out0 + ((size_t)b*SEQ + i0)*ATTN;
  #pragma unroll
  for (int fm=0; fm<2; fm++)
    #pragma unroll
    for (int fn=0; fn<8; fn++)
      #pragma unroll
      for (int mi=0; mi<4; mi++)
        dst[(size_t)(wm*32 + fm*16 + lk*4 + mi)*ATTN + wn*128 + fn*16 + lrow] = tanh_fast(acc[fm][fn][mi]);
}

extern "C" void kernel_launch(void* const* d_in, const int* in_sizes, int n_in,
                              void* d_out, int out_size, void* d_ws, size_t ws_size,
                              hipStream_t stream){
  const float* x  = (const float*)d_in[0];
  const float* Wq = (const float*)d_in[1];
  const float* bq = (const float*)d_in[2];
  const float* Wk = (const float*)d_in[3];
  const float* bk = (const float*)d_in[4];
  const float* Wv = (const float*)d_in[5];
  const float* bv = (const float*)d_in[6];

  float* out0 = (float*)d_out;                        // [8,2048,512]  tanh(context)   33.55 MB
  float* out1 = out0 + (size_t)NB*SEQ*ATTN;           // [8,2048,2048] probs          134.2 MB

  __half* qh  = (__half*)out0;
  __half* kh  = (__half*)out0 + (size_t)MROWS*ATTN;
  __half* xh  = (__half*)out1;
  __half* whT = (__half*)((char*)out1 + 33554432);
  __half* vh  = (__half*)((char*)out1 + 36700160);
  __half* vT  = (__half*)d_ws;

  k_cast_x     <<<8192,        256, 0, stream>>>(x, xh);
  k_transpose_w<<<dim3(512,3), 256, 0, stream>>>(Wq, Wk, Wv, whT);
  k_proj       <<<dim3(12,128),256, 0, stream>>>(xh, whT, bq, bk, bv, qh, kh, vh);
  k_transpose_v<<<dim3(256,8), 256, 0, stream>>>(vh, vT);
  k_scores     <<<512,        1024, 0, stream>>>(qh, kh, out1);
  k_pv         <<<256,         512, 0, stream>>>(out1, vT, out0);
}

// Round 7
// 403.783 us; speedup vs baseline: 1.0156x; 1.0010x over previous
//
#include <hip/hip_runtime.h>
#include <hip/hip_fp16.h>
#include <cstdint>

#define HIDDEN 1024
#define ATTN   512
#define NB     8
#define SEQ    2048
#define MROWS  (NB*SEQ)   // 16384

typedef _Float16 f16x8 __attribute__((ext_vector_type(8)));
typedef _Float16 f16x4 __attribute__((ext_vector_type(4)));
typedef float    f32x4 __attribute__((ext_vector_type(4)));

__device__ __forceinline__ float tanh_fast(float x){
  float e = __expf(2.0f*x);
  return 1.0f - 2.0f/(e + 1.0f);
}

__device__ __forceinline__ void gload16(const void* g, void* l){
  __builtin_amdgcn_global_load_lds((const __attribute__((address_space(1))) void*)g,
                                   (__attribute__((address_space(3))) void*)l, 16, 0, 0);
}

// ---------------- K0a: cast inputs f32 -> fp16 ----------------
__global__ __launch_bounds__(256) void k_cast_x(const float* __restrict__ x, __half* __restrict__ xh){
  size_t i = (size_t)blockIdx.x*256 + threadIdx.x;
  const float4* src = reinterpret_cast<const float4*>(x) + i*2;
  float4 a = src[0], b = src[1];
  f16x8 h;
  h[0]=(_Float16)a.x; h[1]=(_Float16)a.y; h[2]=(_Float16)a.z; h[3]=(_Float16)a.w;
  h[4]=(_Float16)b.x; h[5]=(_Float16)b.y; h[6]=(_Float16)b.z; h[7]=(_Float16)b.w;
  reinterpret_cast<f16x8*>(xh)[i] = h;
}

// ---------------- K0b: W[1024][512] f32 -> WhT[512][1024] fp16 (x3) ----------------
__global__ __launch_bounds__(256) void k_transpose_w(const float* __restrict__ Wq, const float* __restrict__ Wk,
                                                     const float* __restrict__ Wv, __half* __restrict__ whT){
  __shared__ float lds[32][33];
  int which = blockIdx.y;
  const float* W = which==0 ? Wq : (which==1 ? Wk : Wv);
  int tr = blockIdx.x >> 4;
  int tc = blockIdx.x & 15;
  int t = threadIdx.x;
  {
    int r = t >> 3, c4 = (t & 7)*4;
    float4 v = *reinterpret_cast<const float4*>(W + (size_t)(tr*32 + r)*ATTN + tc*32 + c4);
    lds[r][c4+0]=v.x; lds[r][c4+1]=v.y; lds[r][c4+2]=v.z; lds[r][c4+3]=v.w;
  }
  __syncthreads();
  {
    int n = t >> 3, k4 = (t & 7)*4;
    ushort4 u;
    u.x = __half_as_ushort(__float2half(lds[k4+0][n]));
    u.y = __half_as_ushort(__float2half(lds[k4+1][n]));
    u.z = __half_as_ushort(__float2half(lds[k4+2][n]));
    u.w = __half_as_ushort(__float2half(lds[k4+3][n]));
    *reinterpret_cast<ushort4*>(whT + (size_t)which*ATTN*HIDDEN + (size_t)(tc*32 + n)*HIDDEN + tr*32 + k4) = u;
  }
}

// ---------------- K1: fused QKV projection, q/k/v = tanh(x@W + b), fp16 out ----------------
__global__ __launch_bounds__(256,3) void k_proj(const __half* __restrict__ xh, const __half* __restrict__ whT,
                                                const float* __restrict__ bq, const float* __restrict__ bk,
                                                const float* __restrict__ bv,
                                                __half* __restrict__ qh, __half* __restrict__ kh, __half* __restrict__ vh){
  __shared__ __align__(16) _Float16 lA[128*64];   // 16 KB
  __shared__ __align__(16) _Float16 lB[128*64];   // 16 KB
  int nt = blockIdx.x;             // 0..11 : which = nt>>2, 128-col slab = nt&3
  int m0 = blockIdx.y * 128;
  int which = nt >> 2;
  int ncol0 = (nt & 3) * 128;
  int t = threadIdx.x;
  int w = t >> 6, lane = t & 63;
  int lrow = lane & 15, lk = lane >> 4;
  int wm = w >> 1, wn = w & 1;

  int rr = lane >> 3;
  int ss = (lane & 7) ^ rr;
  const __half* Abase = xh + (size_t)(m0 + w*32 + rr)*HIDDEN + ss*8;
  const __half* Bbase = whT + (size_t)which*ATTN*HIDDEN + (size_t)(ncol0 + w*32 + rr)*HIDDEN + ss*8;
  _Float16* lAw = &lA[(w*32)*64];
  _Float16* lBw = &lB[(w*32)*64];

  f32x4 acc[4][4];
  #pragma unroll
  for (int i=0;i<4;i++)
    #pragma unroll
    for (int j=0;j<4;j++) acc[i][j] = f32x4{0.f,0.f,0.f,0.f};

  for (int k0 = 0; k0 < HIDDEN; k0 += 64){
    __syncthreads();
    #pragma unroll
    for (int c=0; c<4; c++){
      gload16(Abase + (size_t)c*8*HIDDEN + k0, &lAw[c*8*64]);
      gload16(Bbase + (size_t)c*8*HIDDEN + k0, &lBw[c*8*64]);
    }
    __syncthreads();
    #pragma unroll
    for (int u=0; u<2; u++){
      f16x8 af[4], bf[4];
      #pragma unroll
      for (int fm=0; fm<4; fm++){
        int row = wm*64 + fm*16 + lrow;
        af[fm] = *(const f16x8*)&lA[row*64 + (((u*4 + lk) ^ (row & 7))*8)];
      }
      #pragma unroll
      for (int fn=0; fn<4; fn++){
        int row = wn*64 + fn*16 + lrow;
        bf[fn] = *(const f16x8*)&lB[row*64 + (((u*4 + lk) ^ (row & 7))*8)];
      }
      #pragma unroll
      for (int fm=0; fm<4; fm++)
        #pragma unroll
        for (int fn=0; fn<4; fn++)
          acc[fm][fn] = __builtin_amdgcn_mfma_f32_16x16x32_f16(af[fm], bf[fn], acc[fm][fn], 0,0,0);
    }
  }

  const float* bias = which==0 ? bq : (which==1 ? bk : bv);
  __half* dst = which==0 ? qh : (which==1 ? kh : vh);
  #pragma unroll
  for (int fn=0; fn<4; fn++){
    int col = ncol0 + wn*64 + fn*16 + lrow;
    float bb = bias[col];
    #pragma unroll
    for (int fm=0; fm<4; fm++)
      #pragma unroll
      for (int mi=0; mi<4; mi++){
        int row = m0 + wm*64 + fm*16 + lk*4 + mi;
        dst[(size_t)row*ATTN + col] = __float2half(tanh_fast(acc[fm][fn][mi] + bb));
      }
  }
}

// ---------------- K1b: vh[16384][512] -> vT[8][512][2048] (per-batch transpose) ----------------
__global__ __launch_bounds__(256) void k_transpose_v(const __half* __restrict__ vh, __half* __restrict__ vT){
  __shared__ _Float16 lds[64][80];
  int r0 = blockIdx.x * 64;
  int c0 = blockIdx.y * 64;
  int b = r0 / SEQ, j0 = r0 % SEQ;
  int t = threadIdx.x;
  #pragma unroll
  for (int it=0; it<2; it++){
    int g = it*256 + t;
    int r = g >> 3, s = g & 7;
    f16x8 v = *(const f16x8*)(vh + (size_t)(r0 + r)*ATTN + c0 + s*8);
    #pragma unroll
    for (int i=0;i<8;i++) lds[s*8+i][r] = v[i];
  }
  __syncthreads();
  #pragma unroll
  for (int it=0; it<2; it++){
    int g = it*256 + t;
    int ar = g >> 3, s = g & 7;
    f16x8 v = *(const f16x8*)&lds[ar][s*8];
    *(f16x8*)(vT + ((size_t)b*ATTN + c0 + ar)*SEQ + j0 + s*8) = v;
  }
}

// ---------------- K2f: FUSED scores+softmax+PV ----------------
// 32 q-rows/block, 16 waves. QK^T swapped-operand (full 2048-key row in regs),
// no-max softmax (|s|<=22.63 -> f32-safe), nontemporal probs stores,
// P -> 128KB swizzled LDS fp16, then PV: wave w owns out-cols [w*32, w*32+32).
__global__ __launch_bounds__(1024,4) void k_attn(const __half* __restrict__ qh, const __half* __restrict__ kh,
                                                 const __half* __restrict__ vT,
                                                 float* __restrict__ probs, float* __restrict__ out0){
  __shared__ __align__(16) _Float16 Plds[32*2048];   // 128 KB; phys 16B-slot = slot ^ (row&7)
  __shared__ float red[16][32];
  int bid = blockIdx.x;
  int b  = bid & 7;            // XCD pin: kh[b] + vT[b] = 4 MB resident in one XCD L2
  int i0 = (bid >> 3) * 32;
  int t = threadIdx.x;
  int w = t >> 6, lane = t & 63;
  int lrow = lane & 15, lk = lane >> 4;
  size_t qrow0 = (size_t)b*SEQ + i0;
  size_t krow0 = (size_t)b*SEQ + w*128;

  // ---- QK^T: S^T = mfma(K_frag, Q_frag); lane holds 4 consecutive keys per q-row
  f32x4 acc[2][8];
  #pragma unroll
  for (int i=0;i<2;i++)
    #pragma unroll
    for (int j=0;j<8;j++) acc[i][j] = f32x4{0.f,0.f,0.f,0.f};

  for (int k0 = 0; k0 < ATTN; k0 += 32){
    f16x8 aq0 = *(const f16x8*)(qh + (qrow0 + lrow)*ATTN      + k0 + lk*8);
    f16x8 aq1 = *(const f16x8*)(qh + (qrow0 + 16 + lrow)*ATTN + k0 + lk*8);
    #pragma unroll
    for (int fn=0; fn<8; fn++){
      f16x8 kf = *(const f16x8*)(kh + (krow0 + fn*16 + lrow)*ATTN + k0 + lk*8);
      acc[0][fn] = __builtin_amdgcn_mfma_f32_16x16x32_f16(kf, aq0, acc[0][fn], 0,0,0);
      acc[1][fn] = __builtin_amdgcn_mfma_f32_16x16x32_f16(kf, aq1, acc[1][fn], 0,0,0);
    }
  }

  // ---- softmax without max-pass: e = exp(s*scale), s in [-22.63, 22.63]
  const float scale = 0.044194173824159216f;   // 1/sqrt(512)
  float sm[2];
  #pragma unroll
  for (int nf=0;nf<2;nf++){
    float s = 0.f;
    #pragma unroll
    for (int fn=0;fn<8;fn++)
      #pragma unroll
      for (int mi=0;mi<4;mi++){
        float e = __expf(acc[nf][fn][mi] * scale);
        acc[nf][fn][mi] = e;
        s += e;
      }
    s += __shfl_xor(s, 16);
    s += __shfl_xor(s, 32);
    sm[nf] = s;
  }
  if (lane < 16){ red[w][lane] = sm[0]; red[w][16 + lane] = sm[1]; }
  __syncthreads();
  float inv[2];
  #pragma unroll
  for (int nf=0;nf<2;nf++){
    float tot = 0.f;
    #pragma unroll
    for (int ww=0; ww<16; ww++) tot += red[ww][nf*16 + lrow];
    inv[nf] = 1.0f / tot;
  }

  // ---- probs global (nontemporal) + P -> LDS fp16 (swizzled)
  float* dst = probs + (size_t)b*SEQ*SEQ;
  #pragma unroll
  for (int nf=0;nf<2;nf++){
    int prow = nf*16 + lrow;
    size_t rowoff = (size_t)(i0 + prow)*SEQ + w*128 + lk*4;
    f32x4 iv = {inv[nf], inv[nf], inv[nf], inv[nf]};
    #pragma unroll
    for (int fn=0;fn<8;fn++){
      f32x4 v = acc[nf][fn] * iv;
      __builtin_nontemporal_store(v, (f32x4*)(dst + rowoff + fn*16));
      f16x4 h;
      h[0]=(_Float16)v[0]; h[1]=(_Float16)v[1]; h[2]=(_Float16)v[2]; h[3]=(_Float16)v[3];
      int slot = (w*16 + fn*2 + (lk>>1)) ^ (prow & 7);
      *(f16x4*)&Plds[prow*2048 + slot*8 + (lk&1)*4] = h;
    }
  }
  __syncthreads();

  // ---- PV: wave w -> cols [w*32, w*32+32); K-loop over 2048 keys, 32/iter
  f32x4 pacc[2][2];
  #pragma unroll
  for (int i=0;i<2;i++)
    #pragma unroll
    for (int j=0;j<2;j++) pacc[i][j] = f32x4{0.f,0.f,0.f,0.f};

  const __half* vb = vT + (size_t)b*ATTN*SEQ;
  const __half* v0 = vb + (size_t)(w*32 + lrow)*SEQ      + lk*8;
  const __half* v1 = vb + (size_t)(w*32 + 16 + lrow)*SEQ + lk*8;
  for (int kk = 0; kk < 64; kk++){
    f16x8 pa[2];
    #pragma unroll
    for (int nf=0;nf<2;nf++){
      int row = nf*16 + lrow;
      int phys = (kk*4 + lk) ^ (row & 7);
      pa[nf] = *(const f16x8*)&Plds[row*2048 + phys*8];
    }
    f16x8 b0 = *(const f16x8*)(v0 + kk*32);
    f16x8 b1 = *(const f16x8*)(v1 + kk*32);
    pacc[0][0] = __builtin_amdgcn_mfma_f32_16x16x32_f16(pa[0], b0, pacc[0][0], 0,0,0);
    pacc[1][0] = __builtin_amdgcn_mfma_f32_16x16x32_f16(pa[1], b0, pacc[1][0], 0,0,0);
    pacc[0][1] = __builtin_amdgcn_mfma_f32_16x16x32_f16(pa[0], b1, pacc[0][1], 0,0,0);
    pacc[1][1] = __builtin_amdgcn_mfma_f32_16x16x32_f16(pa[1], b1, pacc[1][1], 0,0,0);
  }

  #pragma unroll
  for (int nf=0;nf<2;nf++)
    #pragma unroll
    for (int cf=0;cf<2;cf++)
      #pragma unroll
      for (int mi=0;mi<4;mi++)
        out0[(qrow0 + nf*16 + lk*4 + mi)*ATTN + w*32 + cf*16 + lrow] = tanh_fast(pacc[nf][cf][mi]);
}

// ---------------- Fallback K2: scores + softmax -> probs (round-5 path) ----------------
__global__ __launch_bounds__(1024,4) void k_scores(const __half* __restrict__ qh, const __half* __restrict__ kh,
                                                   float* __restrict__ probs){
  __shared__ float red[16][32];
  int bid = blockIdx.x;
  int b  = bid & 7;
  int i0 = (bid >> 3) * 32;
  int t = threadIdx.x;
  int w = t >> 6, lane = t & 63;
  int lrow = lane & 15, lk = lane >> 4;
  size_t qrow0 = (size_t)b*SEQ + i0;
  size_t krow0 = (size_t)b*SEQ + w*128;

  f32x4 acc[2][8];
  #pragma unroll
  for (int i=0;i<2;i++)
    #pragma unroll
    for (int j=0;j<8;j++) acc[i][j] = f32x4{0.f,0.f,0.f,0.f};

  for (int k0 = 0; k0 < ATTN; k0 += 32){
    f16x8 aq0 = *(const f16x8*)(qh + (qrow0 + lrow)*ATTN      + k0 + lk*8);
    f16x8 aq1 = *(const f16x8*)(qh + (qrow0 + 16 + lrow)*ATTN + k0 + lk*8);
    #pragma unroll
    for (int fn=0; fn<8; fn++){
      f16x8 kf = *(const f16x8*)(kh + (krow0 + fn*16 + lrow)*ATTN + k0 + lk*8);
      acc[0][fn] = __builtin_amdgcn_mfma_f32_16x16x32_f16(kf, aq0, acc[0][fn], 0,0,0);
      acc[1][fn] = __builtin_amdgcn_mfma_f32_16x16x32_f16(kf, aq1, acc[1][fn], 0,0,0);
    }
  }

  const float scale = 0.044194173824159216f;
  float sm[2];
  #pragma unroll
  for (int nf=0;nf<2;nf++){
    float s = 0.f;
    #pragma unroll
    for (int fn=0;fn<8;fn++)
      #pragma unroll
      for (int mi=0;mi<4;mi++){
        float e = __expf(acc[nf][fn][mi] * scale);
        acc[nf][fn][mi] = e;
        s += e;
      }
    s += __shfl_xor(s, 16);
    s += __shfl_xor(s, 32);
    sm[nf] = s;
  }
  if (lane < 16){ red[w][lane] = sm[0]; red[w][16 + lane] = sm[1]; }
  __syncthreads();
  float inv[2];
  #pragma unroll
  for (int nf=0;nf<2;nf++){
    float tot = 0.f;
    #pragma unroll
    for (int ww=0; ww<16; ww++) tot += red[ww][nf*16 + lrow];
    inv[nf] = 1.0f / tot;
  }
  float* dst = probs + (size_t)b*SEQ*SEQ;
  #pragma unroll
  for (int nf=0;nf<2;nf++){
    size_t rowoff = (size_t)(i0 + nf*16 + lrow)*SEQ + w*128 + lk*4;
    f32x4 iv = {inv[nf], inv[nf], inv[nf], inv[nf]};
    #pragma unroll
    for (int fn=0;fn<8;fn++){
      f32x4 v = acc[nf][fn] * iv;
      __builtin_nontemporal_store(v, (f32x4*)(dst + rowoff + fn*16));
    }
  }
}

// ---------------- Fallback K3: context = probs @ v ----------------
__global__ __launch_bounds__(512,2) void k_pv(const float* __restrict__ probs, const __half* __restrict__ vT,
                                              float* __restrict__ out0){
  __shared__ __align__(16) _Float16 lA[64*64];
  int bid = blockIdx.x;
  int b  = bid & 7;
  int i0 = (bid >> 3) * 64;
  int t = threadIdx.x;
  int w = t >> 6, lane = t & 63;
  int lrow = lane & 15, lk = lane >> 4;
  int wm = w >> 2, wn = w & 3;
  int sr = t >> 3, ssc = t & 7;

  const float*  psrc  = probs + ((size_t)b*SEQ + i0 + sr)*SEQ + ssc*8;
  const __half* vbase = vT + (size_t)b*ATTN*SEQ;
  int dst_sl = (ssc ^ (sr & 7)) * 8;

  f32x4 acc[2][8];
  #pragma unroll
  for (int i=0;i<2;i++)
    #pragma unroll
    for (int j=0;j<8;j++) acc[i][j] = f32x4{0.f,0.f,0.f,0.f};

  float4 p0 = *(const float4*)(psrc);
  float4 p1 = *(const float4*)(psrc + 4);

  for (int k0 = 0; k0 < SEQ; k0 += 64){
    f16x8 hv;
    hv[0]=(_Float16)p0.x; hv[1]=(_Float16)p0.y; hv[2]=(_Float16)p0.z; hv[3]=(_Float16)p0.w;
    hv[4]=(_Float16)p1.x; hv[5]=(_Float16)p1.y; hv[6]=(_Float16)p1.z; hv[7]=(_Float16)p1.w;
    __syncthreads();
    *(f16x8*)&lA[sr*64 + dst_sl] = hv;
    __syncthreads();
    if (k0 + 64 < SEQ){
      p0 = *(const float4*)(psrc + k0 + 64);
      p1 = *(const float4*)(psrc + k0 + 68);
    }
    #pragma unroll
    for (int u=0; u<2; u++){
      f16x8 af[2];
      #pragma unroll
      for (int fm=0; fm<2; fm++){
        int row = wm*32 + fm*16 + lrow;
        af[fm] = *(const f16x8*)&lA[row*64 + (((u*4 + lk) ^ (row & 7))*8)];
      }
      #pragma unroll
      for (int fn=0; fn<8; fn++){
        f16x8 bv8 = *(const f16x8*)(vbase + (size_t)(wn*128 + fn*16 + lrow)*SEQ + k0 + u*32 + lk*8);
        #pragma unroll
        for (int fm=0; fm<2; fm++)
          acc[fm][fn] = __builtin_amdgcn_mfma_f32_16x16x32_f16(af[fm], bv8, acc[fm][fn], 0,0,0);
      }
    }
  }

  float* dst = out0 + ((size_t)b*SEQ + i0)*ATTN;
  #pragma unroll
  for (int fm=0; fm<2; fm++)
    #pragma unroll
    for (int fn=0; fn<8; fn++)
      #pragma unroll
      for (int mi=0; mi<4; mi++)
        dst[(size_t)(wm*32 + fm*16 + lk*4 + mi)*ATTN + wn*128 + fn*16 + lrow] = tanh_fast(acc[fm][fn][mi]);
}

extern "C" void kernel_launch(void* const* d_in, const int* in_sizes, int n_in,
                              void* d_out, int out_size, void* d_ws, size_t ws_size,
                              hipStream_t stream){
  const float* x  = (const float*)d_in[0];
  const float* Wq = (const float*)d_in[1];
  const float* bq = (const float*)d_in[2];
  const float* Wk = (const float*)d_in[3];
  const float* bk = (const float*)d_in[4];
  const float* Wv = (const float*)d_in[5];
  const float* bv = (const float*)d_in[6];

  float* out0 = (float*)d_out;                        // [8,2048,512]  tanh(context)   33.55 MB
  float* out1 = out0 + (size_t)NB*SEQ*ATTN;           // [8,2048,2048] probs          134.2 MB

  const size_t SZ = 16777216;                         // 16.78 MB
  char* ws = (char*)d_ws;
  // out1 region (written only by the probs-producing kernel): xh | whT | vh overlay
  __half* xh  = (__half*)out1;
  __half* whT = (__half*)((char*)out1 + 2*SZ);
  __half* vh  = (__half*)((char*)out1 + 2*SZ + 3145728);
  __half* vT  = (__half*)ws;

  if (ws_size >= 3*SZ){
    // FUSED path: qh/kh in d_ws (out0 must stay clean — k_attn writes it while reading qh/kh)
    __half* qh = (__half*)(ws + SZ);
    __half* kh = (__half*)(ws + 2*SZ);
    k_cast_x     <<<8192,        256, 0, stream>>>(x, xh);
    k_transpose_w<<<dim3(512,3), 256, 0, stream>>>(Wq, Wk, Wv, whT);
    k_proj       <<<dim3(12,128),256, 0, stream>>>(xh, whT, bq, bk, bv, qh, kh, vh);
    k_transpose_v<<<dim3(256,8), 256, 0, stream>>>(vh, vT);
    k_attn       <<<512,        1024, 0, stream>>>(qh, kh, vT, out1, out0);
  } else {
    // FALLBACK (round-5 structure): qh/kh overlay out0, separate k_scores + k_pv
    __half* qh = (__half*)out0;
    __half* kh = (__half*)out0 + (size_t)MROWS*ATTN;
    k_cast_x     <<<8192,        256, 0, stream>>>(x, xh);
    k_transpose_w<<<dim3(512,3), 256, 0, stream>>>(Wq, Wk, Wv, whT);
    k_proj       <<<dim3(12,128),256, 0, stream>>>(xh, whT, bq, bk, bv, qh, kh, vh);
    k_transpose_v<<<dim3(256,8), 256, 0, stream>>>(vh, vT);
    k_scores     <<<512,        1024, 0, stream>>>(qh, kh, out1);
    k_pv         <<<256,         512, 0, stream>>>(out1, vT, out0);
  }
}